// Round 1
// baseline (43.157 us; speedup 1.0000x reference)
//
#include <hip/hip_runtime.h>
#include <math.h>

// Problem constants (from reference)
#define NBATCH 32
#define NBANDS 5
#define NC 64
#define NT 128
// d_s = 16 -> 1/sqrt(d_s) = 0.25

// Output layout: P_func (32,128,64,64) flat = 16777216 floats, then
// embeddings_mean (32,128,64) flat = 262144 floats.
#define PFUNC_ELEMS (32*128*64*64)

// ws layout (floats):
//   [0,128)   : adjacency bitmask, 64 x uint64 (row i -> bit j set iff adj[i][j]>0)
//   [128,133) : AC[n] = (Wq W_e[n]) . (Wk W_e[n])
//   [136,141) : BC[n] = (Wq b_e[n]) . (Wk W_e[n])

__global__ void bfp_prep_kernel(const float* __restrict__ adj,
                                const float* __restrict__ We,
                                const float* __restrict__ be,
                                const float* __restrict__ Wq,
                                const float* __restrict__ Wk,
                                float* __restrict__ ws) {
    int tid = threadIdx.x;
    if (tid < 64) {
        unsigned long long m = 0ull;
        #pragma unroll 8
        for (int j = 0; j < 64; ++j)
            if (adj[tid * 64 + j] > 0.f) m |= (1ull << j);
        ((unsigned long long*)ws)[tid] = m;
    }
    if (tid >= 64 && tid < 64 + NBANDS * 16) {
        int k = tid - 64;
        int n = k >> 4;      // band
        int s = k & 15;      // d_s index
        float u = 0.f, v = 0.f, w = 0.f;
        for (int d = 0; d < 64; ++d) {
            float wq = Wq[s * 64 + d];
            float wk = Wk[s * 64 + d];
            float we = We[n * 64 + d];
            float bb = be[n * 64 + d];
            u += wq * we;   // A_s
            v += wk * we;   // C_s
            w += wq * bb;   // B_s
        }
        float ac = u * v;
        float bc = w * v;
        // reduce over the 16 lanes of this band (16-aligned lane groups)
        #pragma unroll
        for (int mask = 8; mask >= 1; mask >>= 1) {
            ac += __shfl_xor(ac, mask);
            bc += __shfl_xor(bc, mask);
        }
        if (s == 0) {
            ws[128 + n] = ac;
            ws[136 + n] = bc;
        }
    }
}

__global__ __launch_bounds__(256) void bfp_main_kernel(
        const float* __restrict__ x,      // (32,5,64,128)
        const float* __restrict__ amask,  // (32,128,5)
        const float* __restrict__ alpha,  // (32,128,5)
        const float* __restrict__ We,     // (5,64)
        const float* __restrict__ be,     // (5,64)
        const float* __restrict__ ws,
        float* __restrict__ out) {
    const int bt = blockIdx.x;            // 0..4095
    const int b = bt >> 7;
    const int t = bt & 127;
    const int tid = threadIdx.x;

    __shared__ float x_s[NBANDS][64];
    __shared__ float g_s[NBANDS][64];
    __shared__ float w_s[NBANDS];
    __shared__ float mask_s[NBANDS];
    __shared__ float xbar_s[NBANDS];

    // stage x_t[b,t,n,c] = x[b,n,c,t]
    for (int idx = tid; idx < NBANDS * 64; idx += 256) {
        int n = idx >> 6, c = idx & 63;
        x_s[n][c] = x[(((size_t)b * NBANDS + n) * 64 + c) * 128 + t];
    }
    if (tid < NBANDS) {
        float mk = amask[((size_t)b * 128 + t) * NBANDS + tid];
        mask_s[tid] = mk;
        w_s[tid] = alpha[((size_t)b * 128 + t) * NBANDS + tid] * mk;
    }
    __syncthreads();

    // per-row softmax logits coefficient: g_i = 0.25*(AC_n * x_i + BC_n)
    for (int idx = tid; idx < NBANDS * 64; idx += 256) {
        int n = idx >> 6, i = idx & 63;
        g_s[n][i] = 0.25f * (ws[128 + n] * x_s[n][i] + ws[136 + n]);
    }
    // xbar_n = mean_c x (wave 0 does 5 full-wave reductions)
    if (tid < 64) {
        for (int n = 0; n < NBANDS; ++n) {
            float v = x_s[n][tid];
            #pragma unroll
            for (int mask = 32; mask >= 1; mask >>= 1) v += __shfl_xor(v, mask);
            if (tid == 0) xbar_s[n] = v * (1.f / 64.f);
        }
    }
    __syncthreads();

    // embeddings_mean[b,t,d]
    if (tid < 64) {
        float cnt = 0.f, acc = 0.f;
        #pragma unroll
        for (int n = 0; n < NBANDS; ++n) {
            cnt += mask_s[n];
            acc += mask_s[n] * (xbar_s[n] * We[n * 64 + tid] + be[n * 64 + tid]);
        }
        cnt = fmaxf(cnt, 1.f);
        out[PFUNC_ELEMS + ((size_t)b * 128 + t) * 64 + tid] = acc / cnt;
    }

    // P_func: thread owns row i = tid>>2, 16 columns starting at (tid&3)*16
    const int i = tid >> 2;
    const int jq = tid & 3;
    const int j0 = jq << 4;
    const unsigned long long adjrow = ((const unsigned long long*)ws)[i];
    const unsigned adjbits = (unsigned)((adjrow >> j0) & 0xFFFFull);

    float acc[16];
    #pragma unroll
    for (int jj = 0; jj < 16; ++jj) acc[jj] = 0.f;

    for (int n = 0; n < NBANDS; ++n) {
        const float gi = g_s[n][i];
        float xv[16];
        #pragma unroll
        for (int jj = 0; jj < 16; ++jj) xv[jj] = x_s[n][j0 + jj];

        // masked row max (constant-in-j terms cancel in softmax)
        float m = -INFINITY;
        #pragma unroll
        for (int jj = 0; jj < 16; ++jj)
            if ((adjbits >> jj) & 1) m = fmaxf(m, gi * xv[jj]);
        m = fmaxf(m, __shfl_xor(m, 1));
        m = fmaxf(m, __shfl_xor(m, 2));

        float Z = 0.f;
        float p[16];
        #pragma unroll
        for (int jj = 0; jj < 16; ++jj) {
            float v = ((adjbits >> jj) & 1) ? __expf(gi * xv[jj] - m) : 0.f;
            p[jj] = v;
            Z += v;
        }
        Z += __shfl_xor(Z, 1);
        Z += __shfl_xor(Z, 2);

        const float sc = w_s[n] / Z;   // Z>0 guaranteed (self-loops)
        #pragma unroll
        for (int jj = 0; jj < 16; ++jj) acc[jj] += p[jj] * sc;
    }

    float4* outp = (float4*)(out + ((size_t)bt * 64 + i) * 64 + j0);
    #pragma unroll
    for (int q = 0; q < 4; ++q)
        outp[q] = make_float4(acc[q * 4], acc[q * 4 + 1], acc[q * 4 + 2], acc[q * 4 + 3]);
}

extern "C" void kernel_launch(void* const* d_in, const int* in_sizes, int n_in,
                              void* d_out, int out_size, void* d_ws, size_t ws_size,
                              hipStream_t stream) {
    const float* x     = (const float*)d_in[0];
    const float* adj   = (const float*)d_in[1];
    const float* amask = (const float*)d_in[2];
    const float* alpha = (const float*)d_in[3];
    const float* We    = (const float*)d_in[4];
    const float* be    = (const float*)d_in[5];
    const float* Wq    = (const float*)d_in[6];
    const float* Wk    = (const float*)d_in[7];
    float* ws  = (float*)d_ws;
    float* out = (float*)d_out;

    bfp_prep_kernel<<<1, 160, 0, stream>>>(adj, We, be, Wq, Wk, ws);
    bfp_main_kernel<<<4096, 256, 0, stream>>>(x, amask, alpha, We, be, ws, out);
}